// Round 9
// baseline (117.152 us; speedup 1.0000x reference)
//
#include <hip/hip_runtime.h>
#include <stdint.h>

// Exact k-subset sampler, pair-per-row layout (R7 structure), zero __syncthreads.
// Wave = 32 rows x 2 lanes (r = lane>>1, p = lane&1), 64-thread blocks.
//   - up-pass split by p (exact OCML); L4 exchanged via shfl_xor (no LDS).
//   - down-pass split by p (fast __expf/__logf; marginals only, thr 2e-2).
//   - sampling: lane p runs sample p. Draw compaction: li1 flat (<=10),
//     li2 flat (feasible j in [max(0,c-4),min(c,4)], Sum c = 8 -> <=12),
//     li3 flat ([max(0,c-2),min(c,2)], Sum c = 8 -> <=16), li4 only c==1.
//     All skipped draws are infeasible (-1e10 can't win) or argmax-of-one =>
//     bitwise-identical samples (PRNG + pruning verified rounds 1-8).
// Single-term conv outputs (conv<3,5> m=4, conv<5,9> m=8) stored as direct
// sums: log(exp(0))=0 exactly (same trick as th2, validated since R3).

__host__ __device__ __forceinline__ void tf2x32(uint32_t k0, uint32_t k1,
                                                uint32_t x0, uint32_t x1,
                                                uint32_t& y0, uint32_t& y1) {
  const uint32_t ks[3] = {k0, k1, k0 ^ k1 ^ 0x1BD11BDAu};
  x0 += ks[0]; x1 += ks[1];
  const int R0[4] = {13, 15, 26, 6};
  const int R1[4] = {17, 29, 16, 24};
#pragma unroll
  for (int i = 0; i < 5; ++i) {
    const int* R = (i & 1) ? R1 : R0;
#pragma unroll
    for (int rr = 0; rr < 4; ++rr) {
      x0 += x1;
      x1 = (x1 << R[rr]) | (x1 >> (32 - R[rr]));
      x1 ^= x0;
    }
    x0 += ks[(i + 1) % 3];
    x1 += ks[(i + 2) % 3] + (uint32_t)(i + 1);
  }
  y0 = x0; y1 = x1;
}

struct TFKeys { uint32_t v[10]; };

// Exact gumbel (OCML logf) — must stay bit-identical to JAX reference.
__device__ __forceinline__ float gumbel_draw(uint32_t sk0, uint32_t sk1,
                                             uint32_t f) {
  uint32_t y0, y1;
  tf2x32(sk0, sk1, 0u, f, y0, y1);
  uint32_t bits = y0 ^ y1;
  uint32_t fb = (bits >> 9) | 0x3f800000u;
  float u = __uint_as_float(fb) - 1.0f;
  const float tiny = 1.17549435e-38f;
  float rr = fmaxf(tiny, u + tiny);
  return -logf(-logf(rr));
}

template<bool FAST> __device__ __forceinline__ float expT(float x) {
  return FAST ? __expf(x) : expf(x);
}
template<bool FAST> __device__ __forceinline__ float logT(float x) {
  return FAST ? __logf(x) : logf(x);
}

// o[m] = logsumexp_j aL[j] + aR[m-j] over in-support j, ascending-j sum.
// LS: last output is a single-term lse -> exact direct sum.
template<int SIN, int SOUT, bool FAST, bool LS>
__device__ __forceinline__ void conv_level(const float (&aL)[SIN],
                                           const float (&aR)[SIN],
                                           float (&o)[SOUT]) {
#pragma unroll
  for (int m = 1; m < SOUT; ++m) {
    if (LS && m == SOUT - 1) { o[m] = aL[SIN - 1] + aR[SIN - 1]; continue; }
    const int jlo = (m - (SIN - 1) > 0) ? (m - (SIN - 1)) : 0;
    const int jhi = (m < SIN - 1) ? m : (SIN - 1);
    float t[SIN];
#pragma unroll
    for (int j = 0; j < SIN; ++j)
      if (j >= jlo && j <= jhi) t[j] = aL[j] + aR[m - j];
    float amax = t[jlo];
#pragma unroll
    for (int j = 0; j < SIN; ++j)
      if (j > jlo && j <= jhi) amax = fmaxf(amax, t[j]);
    float s = 0.0f;
#pragma unroll
    for (int j = 0; j < SIN; ++j)
      if (j >= jlo && j <= jhi) s += expT<FAST>(t[j] - amax);
    o[m] = logT<FAST>(s) + amax;
  }
}

// eo[m] = logsumexp_{j=max(0,m-SSIB+1)..m} ein[j] + sib[m-j]
template<int SSIB, int MLO, int MHI, bool FAST>
__device__ __forceinline__ void ext_level(const float (&ein)[8],
                                          const float* sib, float (&eo)[8]) {
#pragma unroll
  for (int m = MLO; m <= MHI; ++m) {
    const int jlo = (m - (SSIB - 1) > 0) ? (m - (SSIB - 1)) : 0;
    float t[8];
#pragma unroll
    for (int j = 0; j < 8; ++j)
      if (j >= jlo && j <= m) t[j] = ein[j] + sib[m - j];
    float amax = t[jlo];
#pragma unroll
    for (int j = 0; j < 8; ++j)
      if (j > jlo && j <= m) amax = fmaxf(amax, t[j]);
    float s = 0.0f;
#pragma unroll
    for (int j = 0; j < 8; ++j)
      if (j >= jlo && j <= m) s += expT<FAST>(t[j] - amax);
    eo[m] = logT<FAST>(s) + amax;
  }
}

// LDS entry map (stride 32 over r; bank = r%32 -> uniform-entry access is
// 32 banks x 2-way broadcast; divergent-entry access stays in own bank with
// at most 2-way pair alias = free):
//  theta col c        : 0..31
//  L1 m=1, node n1    : 32 + n1   (n1 0..15)
//  L1 m=2, node n1    : 48 + n1
//  L2 node n2, m=1..4 : 64 + n2*4 + (m-1)   (n2 0..7)
//  L3 node n3, m=1..8 : 96 + n3*8 + (m-1)   (n3 0..3)
#define ENT 128

__global__ __launch_bounds__(64, 2) void simple_sampler_kernel(
    const float* __restrict__ scores, float* __restrict__ out,
    int nnodes, TFKeys keys) {
  const int lane = threadIdx.x;
  const int p = lane & 1;        // sample id / subtree id for this lane
  const int r = lane >> 1;       // row-local 0..31
  const int row = blockIdx.x * 32 + r;
  const int node = row >> 3, e = row & 7;
  const int B = nnodes * 8;

  __shared__ float tab[ENT * 32];
#define L(E) tab[(E) * 32 + r]

  // ---- load own-half theta (16 cols), stash to LDS ----
  float th[16];
  const float* sc = scores + node * 256 + e + p * 128;
#pragma unroll
  for (int c = 0; c < 16; ++c) th[c] = sc[c * 8];
#pragma unroll
  for (int c = 0; c < 16; ++c) L(16 * p + c) = th[c];

  // ---- up pass, subtree n4 = p only (exact OCML) ----
  float l1r[8], th2r[8];
#pragma unroll
  for (int n1l = 0; n1l < 8; ++n1l) {
    float tL = th[2 * n1l], tR = th[2 * n1l + 1];
    float amax = fmaxf(tR, tL);              // t0 = thR (j=0), t1 = thL
    float s = expf(tR - amax) + expf(tL - amax);
    l1r[n1l] = logf(s) + amax;
    th2r[n1l] = tL + tR;                      // exact: logf(1.0f)==0.0f
    int n1 = 8 * p + n1l;
    L(32 + n1) = l1r[n1l];
    L(48 + n1) = th2r[n1l];
  }
  float l2r[4][5];
#pragma unroll
  for (int n2l = 0; n2l < 4; ++n2l) {
    float aL[3] = {0.0f, l1r[2 * n2l], th2r[2 * n2l]};
    float aR[3] = {0.0f, l1r[2 * n2l + 1], th2r[2 * n2l + 1]};
    float o5[5];
    conv_level<3, 5, false, true>(aL, aR, o5);
    l2r[n2l][0] = 0.0f;
    int n2 = 4 * p + n2l;
#pragma unroll
    for (int m = 1; m < 5; ++m) { l2r[n2l][m] = o5[m]; L(64 + n2 * 4 + m - 1) = o5[m]; }
  }
  float l3r[2][9];
#pragma unroll
  for (int n3l = 0; n3l < 2; ++n3l) {
    float o9[9];
    conv_level<5, 9, false, true>(l2r[2 * n3l], l2r[2 * n3l + 1], o9);
    l3r[n3l][0] = 0.0f;
    int n3 = 2 * p + n3l;
#pragma unroll
    for (int m = 1; m < 9; ++m) { l3r[n3l][m] = o9[m]; L(96 + n3 * 8 + m - 1) = o9[m]; }
  }

  // Pin ordering: all up-pass LDS writes precede all cross-half LDS reads.
  __builtin_amdgcn_wave_barrier();

  // ---- L4 node p in regs; exchange via shfl (no LDS, no barrier needed) ----
  float A0[9], A1[9];
  {
    float l4o[9];
    conv_level<9, 9, false, false>(l3r[0], l3r[1], l4o);
    A0[0] = 0.0f; A1[0] = 0.0f;
#pragma unroll
    for (int m = 1; m < 9; ++m) {
      float own = l4o[m];
      float oth = __shfl_xor(own, 1);
      A0[m] = p ? oth : own;
      A1[m] = p ? own : oth;
    }
  }

  // ---- logZ (marginals only -> fast) ----
  float logZ;
  {
    float tv[9];
#pragma unroll
    for (int j = 0; j < 9; ++j) tv[j] = A0[j] + A1[8 - j];
    float amax = tv[0];
#pragma unroll
    for (int j = 1; j < 9; ++j) amax = fmaxf(amax, tv[j]);
    float s = 0.0f;
#pragma unroll
    for (int j = 0; j < 9; ++j) s += __expf(tv[j] - amax);
    logZ = __logf(s) + amax;
  }

  // ---- down pass, subtrees n3 in {2p, 2p+1} (fast path; marginals only) ----
  {
    float e4v[8];
    e4v[0] = 0.0f;
#pragma unroll
    for (int m = 1; m < 8; ++m) e4v[m] = p ? A0[m] : A1[m];  // sibling of n4=p
    float* mb = out + 2 * B * 32 + node * 256 + e;
#pragma unroll
    for (int n3l = 0; n3l < 2; ++n3l) {
      float e3[8];
      ext_level<9, 0, 7, true>(e4v, l3r[n3l ^ 1], e3);
#pragma unroll
      for (int c2 = 0; c2 < 2; ++c2) {
        const int n2l = 2 * n3l + c2;
        float e2v[8];
        ext_level<5, 4, 7, true>(e3, l2r[n2l ^ 1], e2v);
#pragma unroll
        for (int c1i = 0; c1i < 2; ++c1i) {
          const int n1l = 2 * n2l + c1i;
          float sib1[3] = {0.0f, l1r[n1l ^ 1], th2r[n1l ^ 1]};
          float e1m[8];
          ext_level<3, 6, 7, true>(e2v, sib1, e1m);
          const int colL = 16 * p + 2 * n1l;
          {
            float t6 = e1m[6] + th[2 * n1l + 1];
            float t7 = e1m[7];
            float amax = fmaxf(t6, t7);
            float s = __expf(t6 - amax) + __expf(t7 - amax);
            mb[colL * 8] = __expf((th[2 * n1l] + (__logf(s) + amax)) - logZ);
          }
          {
            float t6 = e1m[6] + th[2 * n1l];
            float t7 = e1m[7];
            float amax = fmaxf(t6, t7);
            float s = __expf(t6 - amax) + __expf(t7 - amax);
            mb[(colL + 1) * 8] = __expf((th[2 * n1l + 1] + (__logf(s) + amax)) - logZ);
          }
        }
      }
    }
  }

  // ---- top-down sampling, sample s = p (bit-exact path) ----
  const uint32_t t9 = (uint32_t)(p * B + row) * 9u;
  int c0, c1;
  {  // root, c = 8, static (A0/A1 regs)
    float best = 0.0f; int bj = 0;
#pragma unroll
    for (int j = 0; j < 9; ++j) {
      float g = gumbel_draw(keys.v[0], keys.v[1], t9 + (uint32_t)j);
      float v = (A0[j] + A1[8 - j]) + g;
      if (j == 0) { best = v; } else if (v > best) { best = v; bj = j; }
    }
    c0 = bj; c1 = 8 - bj;
  }
  int c1v[4];
  {  // li1: flat loop, feasible j = 0..c (c==0 -> no draw, bj=0)
    const int n0 = c0 ? c0 + 1 : 0;
    const int n1c = c1 ? c1 + 1 : 0;
    const int tot = n0 + n1c;
    float b0 = -3.0e38f, b1 = -3.0e38f;
    int j0 = 0, j1 = 0;
    for (int t = 0; t < tot; ++t) {
      const bool is1 = (t >= n0);
      const int j = is1 ? (t - n0) : t;
      const int c = is1 ? c1 : c0;
      const int i = is1 ? 1 : 0;
      const int idx = c - j;
      float a = (j == 0) ? 0.0f : L(96 + 16 * i + j - 1);
      float b = (idx == 0) ? 0.0f : L(96 + 16 * i + 8 + idx - 1);
      float g = gumbel_draw(keys.v[2], keys.v[3],
                            2u * t9 + (uint32_t)(9 * i + j));
      float v = (a + b) + g;
      if (is1) { if (v > b1) { b1 = v; j1 = j; } }
      else     { if (v > b0) { b0 = v; j0 = j; } }
    }
    c1v[0] = j0; c1v[1] = c0 - j0; c1v[2] = j1; c1v[3] = c1 - j1;
  }
  // ---- li2: flat compacted over 4 tasks (Sum c = 8 -> T <= 12) ----
  uint32_t c3Pk = 0;   // 8 x 4-bit li3 task counts
  {
    int nA[4], jl4[4];
#pragma unroll
    for (int i = 0; i < 4; ++i) {
      int c = c1v[i];
      int lo = (c - 4 > 0) ? (c - 4) : 0;
      int hi = (c < 4) ? c : 4;
      jl4[i] = lo;
      nA[i] = c ? (hi - lo + 1) : 0;
    }
    const int s1 = nA[0], s2 = s1 + nA[1], s3 = s2 + nA[2];
    const int T = s3 + nA[3];
    const uint32_t sPk = ((uint32_t)s1 << 8) | ((uint32_t)s2 << 16) |
                         ((uint32_t)s3 << 24);
    const uint32_t jloPk = (uint32_t)jl4[0] | ((uint32_t)jl4[1] << 4) |
                           ((uint32_t)jl4[2] << 8) | ((uint32_t)jl4[3] << 12);
    const uint32_t cPk = (uint32_t)c1v[0] | ((uint32_t)c1v[1] << 8) |
                         ((uint32_t)c1v[2] << 16) | ((uint32_t)c1v[3] << 24);
    int curI = 0, bj = 0;
    float best = -3.0e38f;
    for (int t = 0; t < T; ++t) {
      int i = (int)(t >= s1) + (int)(t >= s2) + (int)(t >= s3);
      bool nw = (i != curI);
      int cP = (int)((cPk >> (8 * curI)) & 255u);
      uint32_t fl = ((uint32_t)bj << (8 * curI)) |
                    ((uint32_t)(cP - bj) << (8 * curI + 4));
      c3Pk |= nw ? fl : 0u;
      best = nw ? -3.0e38f : best;
      bj = nw ? 0 : bj;
      curI = i;
      int base = (int)((sPk >> (8 * i)) & 255u);
      int c = (int)((cPk >> (8 * i)) & 255u);
      int j = (int)((jloPk >> (4 * i)) & 15u) + (t - base);
      int idx = c - j;
      float a = j ? L(64 + 8 * i + j - 1) : 0.0f;
      float b = idx ? L(64 + 8 * i + 4 + idx - 1) : 0.0f;
      float g = gumbel_draw(keys.v[4], keys.v[5],
                            4u * t9 + (uint32_t)(9 * i + j));
      float v = (a + b) + g;
      if (v > best) { best = v; bj = j; }
    }
    int cP = (int)((cPk >> (8 * curI)) & 255u);
    c3Pk |= ((uint32_t)bj << (8 * curI)) |
            ((uint32_t)(cP - bj) << (8 * curI + 4));
  }
  // ---- li3: flat compacted over 8 tasks (Sum c = 8 -> T <= 16) ----
  uint64_t pk64 = 0;   // 16 x 4-bit li4 pair counts
  {
    uint64_t sPk = 0;
    uint32_t jloPk = 0;
    int run = 0;
#pragma unroll
    for (int k = 0; k < 8; ++k) {
      int c = (int)((c3Pk >> (4 * k)) & 15u);
      int lo = (c - 2 > 0) ? (c - 2) : 0;
      int hi = (c < 2) ? c : 2;
      jloPk |= (uint32_t)lo << (4 * k);
      sPk |= (uint64_t)(uint32_t)run << (8 * k);
      run += c ? (hi - lo + 1) : 0;
    }
    const int T = run;
    int curI = 0, bj = 0;
    float best = -3.0e38f;
    for (int t = 0; t < T; ++t) {
      int i = 0;
#pragma unroll
      for (int k = 1; k < 8; ++k)
        i += (int)(t >= (int)((sPk >> (8 * k)) & 255u));
      bool nw = (i != curI);
      int cP = (int)((c3Pk >> (4 * curI)) & 15u);
      uint64_t fl = ((uint64_t)(uint32_t)bj << (8 * curI)) |
                    ((uint64_t)(uint32_t)(cP - bj) << (8 * curI + 4));
      pk64 |= nw ? fl : (uint64_t)0;
      best = nw ? -3.0e38f : best;
      bj = nw ? 0 : bj;
      curI = i;
      int base = (int)((sPk >> (8 * i)) & 255u);
      int c = (int)((c3Pk >> (4 * i)) & 15u);
      int j = (int)((jloPk >> (4 * i)) & 15u) + (t - base);
      int idx = c - j;
      float a = j ? L(32 + ((j - 1) << 4) + 2 * i) : 0.0f;
      float b = idx ? L(32 + ((idx - 1) << 4) + 2 * i + 1) : 0.0f;
      float g = gumbel_draw(keys.v[6], keys.v[7],
                            8u * t9 + (uint32_t)(9 * i + j));
      float v = (a + b) + g;
      if (v > best) { best = v; bj = j; }
    }
    int cP = (int)((c3Pk >> (4 * curI)) & 15u);
    pk64 |= ((uint64_t)(uint32_t)bj << (8 * curI)) |
            ((uint64_t)(uint32_t)(cP - bj) << (8 * curI + 4));
  }
  {  // li4: draws ONLY for c==1 leaf pairs (c=0 -> bj=0, c=2 -> bj=1)
    const uint32_t sk0 = keys.v[8], sk1 = keys.v[9];
    const uint32_t fb0 = 16u * t9;
    float* bs = out + p * (B * 32) + node * 256 + e;
    uint64_t lst = 0; int m4 = 0;
#pragma unroll
    for (int i = 0; i < 16; ++i) {
      int c = (int)((uint32_t)(pk64 >> (4 * i)) & 15u);
      if (c == 1) {
        lst |= ((uint64_t)(uint32_t)i) << (4 * m4);
        ++m4;
      } else {
        int bj = c >> 1;                        // 0->0, 2->1
        bs[16 * i] = (float)bj;
        bs[16 * i + 8] = (float)(c - bj);
      }
    }
    for (int tt = 0; tt < m4; ++tt) {
      int i = (int)((lst >> (4 * tt)) & 15u);
      float thL = L(2 * i);
      float thR = L(2 * i + 1);
      uint32_t fb = fb0 + (uint32_t)(i * 9);
      float g0 = gumbel_draw(sk0, sk1, fb);       // j=0: 0 + thR
      float g1 = gumbel_draw(sk0, sk1, fb + 1u);  // j=1: thL + 0
      int bj = ((thL + g1) > (thR + g0)) ? 1 : 0; // first-max: strict >
      bs[16 * i] = (float)bj;
      bs[16 * i + 8] = (float)(1 - bj);
    }
  }
#undef L
}

extern "C" void kernel_launch(void* const* d_in, const int* in_sizes, int n_in,
                              void* d_out, int out_size, void* d_ws, size_t ws_size,
                              hipStream_t stream) {
  const float* scores = (const float*)d_in[0];
  float* out = (float*)d_out;
  const int nnodes = in_sizes[0] / (32 * 8);   // 8192
  const int B = nnodes * 8;                    // 65536 rows

  // key = jax.random.key(42); per level: key, sub = split(key)
  // (partitionable threefry: new = tf(key,(0,0)), sub = tf(key,(0,1)))
  TFKeys K;
  uint32_t k0 = 0u, k1 = 42u;
  for (int t = 0; t < 5; ++t) {
    uint32_t n0, n1, s0, s1;
    tf2x32(k0, k1, 0u, 0u, n0, n1);
    tf2x32(k0, k1, 0u, 1u, s0, s1);
    K.v[2 * t] = s0; K.v[2 * t + 1] = s1;
    k0 = n0; k1 = n1;
  }

  dim3 grid((unsigned)(B / 32)), block(64);
  hipLaunchKernelGGL(simple_sampler_kernel, grid, block, 0, stream,
                     scores, out, nnodes, K);
}

// Round 10
// 113.441 us; speedup vs baseline: 1.0327x; 1.0327x over previous
//
#include <hip/hip_runtime.h>
#include <stdint.h>

// Exact k-subset sampler, pair-per-row layout, zero __syncthreads.
// Wave = 32 rows x 2 lanes (r = lane>>1, p = lane&1), 64-thread blocks.
//   - up-pass split by p (exact OCML); L4 exchanged via shfl_xor (no LDS).
//   - down-pass split by p (fast __expf/__logf; marginals only, thr 2e-2).
//   - sampling: lane p runs sample p. li1 flat-compacted (<=10 draws),
//     li2/li3 static unrolled (low per-draw overhead beats compaction: R9
//     post-mortem), li4 draws only for c==1 pairs.
//     All skipped draws are infeasible (-1e10 can't win) or argmax-of-one =>
//     bitwise-identical samples (PRNG + pruning verified rounds 1-9).
// Single-term conv outputs (conv<3,5> m=4, conv<5,9> m=8) stored as direct
// sums: log(exp(0))=0 exactly (same trick as th2, validated since R3).

__host__ __device__ __forceinline__ void tf2x32(uint32_t k0, uint32_t k1,
                                                uint32_t x0, uint32_t x1,
                                                uint32_t& y0, uint32_t& y1) {
  const uint32_t ks[3] = {k0, k1, k0 ^ k1 ^ 0x1BD11BDAu};
  x0 += ks[0]; x1 += ks[1];
  const int R0[4] = {13, 15, 26, 6};
  const int R1[4] = {17, 29, 16, 24};
#pragma unroll
  for (int i = 0; i < 5; ++i) {
    const int* R = (i & 1) ? R1 : R0;
#pragma unroll
    for (int rr = 0; rr < 4; ++rr) {
      x0 += x1;
      x1 = (x1 << R[rr]) | (x1 >> (32 - R[rr]));
      x1 ^= x0;
    }
    x0 += ks[(i + 1) % 3];
    x1 += ks[(i + 2) % 3] + (uint32_t)(i + 1);
  }
  y0 = x0; y1 = x1;
}

struct TFKeys { uint32_t v[10]; };

// Exact gumbel (OCML logf) — must stay bit-identical to JAX reference.
__device__ __forceinline__ float gumbel_draw(uint32_t sk0, uint32_t sk1,
                                             uint32_t f) {
  uint32_t y0, y1;
  tf2x32(sk0, sk1, 0u, f, y0, y1);
  uint32_t bits = y0 ^ y1;
  uint32_t fb = (bits >> 9) | 0x3f800000u;
  float u = __uint_as_float(fb) - 1.0f;
  const float tiny = 1.17549435e-38f;
  float rr = fmaxf(tiny, u + tiny);
  return -logf(-logf(rr));
}

template<bool FAST> __device__ __forceinline__ float expT(float x) {
  return FAST ? __expf(x) : expf(x);
}
template<bool FAST> __device__ __forceinline__ float logT(float x) {
  return FAST ? __logf(x) : logf(x);
}

// o[m] = logsumexp_j aL[j] + aR[m-j] over in-support j, ascending-j sum.
// LS: last output is a single-term lse -> exact direct sum.
template<int SIN, int SOUT, bool FAST, bool LS>
__device__ __forceinline__ void conv_level(const float (&aL)[SIN],
                                           const float (&aR)[SIN],
                                           float (&o)[SOUT]) {
#pragma unroll
  for (int m = 1; m < SOUT; ++m) {
    if (LS && m == SOUT - 1) { o[m] = aL[SIN - 1] + aR[SIN - 1]; continue; }
    const int jlo = (m - (SIN - 1) > 0) ? (m - (SIN - 1)) : 0;
    const int jhi = (m < SIN - 1) ? m : (SIN - 1);
    float t[SIN];
#pragma unroll
    for (int j = 0; j < SIN; ++j)
      if (j >= jlo && j <= jhi) t[j] = aL[j] + aR[m - j];
    float amax = t[jlo];
#pragma unroll
    for (int j = 0; j < SIN; ++j)
      if (j > jlo && j <= jhi) amax = fmaxf(amax, t[j]);
    float s = 0.0f;
#pragma unroll
    for (int j = 0; j < SIN; ++j)
      if (j >= jlo && j <= jhi) s += expT<FAST>(t[j] - amax);
    o[m] = logT<FAST>(s) + amax;
  }
}

// eo[m] = logsumexp_{j=max(0,m-SSIB+1)..m} ein[j] + sib[m-j]
template<int SSIB, int MLO, int MHI, bool FAST>
__device__ __forceinline__ void ext_level(const float (&ein)[8],
                                          const float* sib, float (&eo)[8]) {
#pragma unroll
  for (int m = MLO; m <= MHI; ++m) {
    const int jlo = (m - (SSIB - 1) > 0) ? (m - (SSIB - 1)) : 0;
    float t[8];
#pragma unroll
    for (int j = 0; j < 8; ++j)
      if (j >= jlo && j <= m) t[j] = ein[j] + sib[m - j];
    float amax = t[jlo];
#pragma unroll
    for (int j = 0; j < 8; ++j)
      if (j > jlo && j <= m) amax = fmaxf(amax, t[j]);
    float s = 0.0f;
#pragma unroll
    for (int j = 0; j < 8; ++j)
      if (j >= jlo && j <= m) s += expT<FAST>(t[j] - amax);
    eo[m] = logT<FAST>(s) + amax;
  }
}

// LDS entry map (stride 32 over r; bank = r%32 -> uniform-entry access is
// 32 banks x 2-way broadcast; divergent-entry access stays in own bank with
// at most 2-way pair alias = free):
//  theta col c        : 0..31
//  L1 m=1, node n1    : 32 + n1   (n1 0..15)
//  L1 m=2, node n1    : 48 + n1
//  L2 node n2, m=1..4 : 64 + n2*4 + (m-1)   (n2 0..7)
//  L3 node n3, m=1..8 : 96 + n3*8 + (m-1)   (n3 0..3)
#define ENT 128

__global__ __launch_bounds__(64, 2) void simple_sampler_kernel(
    const float* __restrict__ scores, float* __restrict__ out,
    int nnodes, TFKeys keys) {
  const int lane = threadIdx.x;
  const int p = lane & 1;        // sample id / subtree id for this lane
  const int r = lane >> 1;       // row-local 0..31
  const int row = blockIdx.x * 32 + r;
  const int node = row >> 3, e = row & 7;
  const int B = nnodes * 8;

  __shared__ float tab[ENT * 32];
#define L(E) tab[(E) * 32 + r]

  // ---- load own-half theta (16 cols), stash to LDS ----
  float th[16];
  const float* sc = scores + node * 256 + e + p * 128;
#pragma unroll
  for (int c = 0; c < 16; ++c) th[c] = sc[c * 8];
#pragma unroll
  for (int c = 0; c < 16; ++c) L(16 * p + c) = th[c];

  // ---- up pass, subtree n4 = p only (exact OCML) ----
  float l1r[8], th2r[8];
#pragma unroll
  for (int n1l = 0; n1l < 8; ++n1l) {
    float tL = th[2 * n1l], tR = th[2 * n1l + 1];
    float amax = fmaxf(tR, tL);              // t0 = thR (j=0), t1 = thL
    float s = expf(tR - amax) + expf(tL - amax);
    l1r[n1l] = logf(s) + amax;
    th2r[n1l] = tL + tR;                      // exact: logf(1.0f)==0.0f
    int n1 = 8 * p + n1l;
    L(32 + n1) = l1r[n1l];
    L(48 + n1) = th2r[n1l];
  }
  float l2r[4][5];
#pragma unroll
  for (int n2l = 0; n2l < 4; ++n2l) {
    float aL[3] = {0.0f, l1r[2 * n2l], th2r[2 * n2l]};
    float aR[3] = {0.0f, l1r[2 * n2l + 1], th2r[2 * n2l + 1]};
    float o5[5];
    conv_level<3, 5, false, true>(aL, aR, o5);
    l2r[n2l][0] = 0.0f;
    int n2 = 4 * p + n2l;
#pragma unroll
    for (int m = 1; m < 5; ++m) { l2r[n2l][m] = o5[m]; L(64 + n2 * 4 + m - 1) = o5[m]; }
  }
  float l3r[2][9];
#pragma unroll
  for (int n3l = 0; n3l < 2; ++n3l) {
    float o9[9];
    conv_level<5, 9, false, true>(l2r[2 * n3l], l2r[2 * n3l + 1], o9);
    l3r[n3l][0] = 0.0f;
    int n3 = 2 * p + n3l;
#pragma unroll
    for (int m = 1; m < 9; ++m) { l3r[n3l][m] = o9[m]; L(96 + n3 * 8 + m - 1) = o9[m]; }
  }

  // Pin ordering: all up-pass LDS writes precede all cross-half LDS reads.
  __builtin_amdgcn_wave_barrier();

  // ---- L4 node p in regs; exchange via shfl (no LDS, no barrier needed) ----
  float A0[9], A1[9];
  {
    float l4o[9];
    conv_level<9, 9, false, false>(l3r[0], l3r[1], l4o);
    A0[0] = 0.0f; A1[0] = 0.0f;
#pragma unroll
    for (int m = 1; m < 9; ++m) {
      float own = l4o[m];
      float oth = __shfl_xor(own, 1);
      A0[m] = p ? oth : own;
      A1[m] = p ? own : oth;
    }
  }

  // ---- logZ (marginals only -> fast) ----
  float logZ;
  {
    float tv[9];
#pragma unroll
    for (int j = 0; j < 9; ++j) tv[j] = A0[j] + A1[8 - j];
    float amax = tv[0];
#pragma unroll
    for (int j = 1; j < 9; ++j) amax = fmaxf(amax, tv[j]);
    float s = 0.0f;
#pragma unroll
    for (int j = 0; j < 9; ++j) s += __expf(tv[j] - amax);
    logZ = __logf(s) + amax;
  }

  // ---- down pass, subtrees n3 in {2p, 2p+1} (fast path; marginals only) ----
  {
    float e4v[8];
    e4v[0] = 0.0f;
#pragma unroll
    for (int m = 1; m < 8; ++m) e4v[m] = p ? A0[m] : A1[m];  // sibling of n4=p
    float* mb = out + 2 * B * 32 + node * 256 + e;
#pragma unroll
    for (int n3l = 0; n3l < 2; ++n3l) {
      float e3[8];
      ext_level<9, 0, 7, true>(e4v, l3r[n3l ^ 1], e3);
#pragma unroll
      for (int c2 = 0; c2 < 2; ++c2) {
        const int n2l = 2 * n3l + c2;
        float e2v[8];
        ext_level<5, 4, 7, true>(e3, l2r[n2l ^ 1], e2v);
#pragma unroll
        for (int c1i = 0; c1i < 2; ++c1i) {
          const int n1l = 2 * n2l + c1i;
          float sib1[3] = {0.0f, l1r[n1l ^ 1], th2r[n1l ^ 1]};
          float e1m[8];
          ext_level<3, 6, 7, true>(e2v, sib1, e1m);
          const int colL = 16 * p + 2 * n1l;
          {
            float t6 = e1m[6] + th[2 * n1l + 1];
            float t7 = e1m[7];
            float amax = fmaxf(t6, t7);
            float s = __expf(t6 - amax) + __expf(t7 - amax);
            mb[colL * 8] = __expf((th[2 * n1l] + (__logf(s) + amax)) - logZ);
          }
          {
            float t6 = e1m[6] + th[2 * n1l];
            float t7 = e1m[7];
            float amax = fmaxf(t6, t7);
            float s = __expf(t6 - amax) + __expf(t7 - amax);
            mb[(colL + 1) * 8] = __expf((th[2 * n1l + 1] + (__logf(s) + amax)) - logZ);
          }
        }
      }
    }
  }

  // ---- top-down sampling, sample s = p (bit-exact path) ----
  const uint32_t t9 = (uint32_t)(p * B + row) * 9u;
  int c0, c1;
  {  // root, c = 8, static (A0/A1 regs)
    float best = 0.0f; int bj = 0;
#pragma unroll
    for (int j = 0; j < 9; ++j) {
      float g = gumbel_draw(keys.v[0], keys.v[1], t9 + (uint32_t)j);
      float v = (A0[j] + A1[8 - j]) + g;
      if (j == 0) { best = v; } else if (v > best) { best = v; bj = j; }
    }
    c0 = bj; c1 = 8 - bj;
  }
  int c1v[4];
  {  // li1: flat loop, feasible j = 0..c (c==0 -> no draw, bj=0)
    const int n0 = c0 ? c0 + 1 : 0;
    const int n1c = c1 ? c1 + 1 : 0;
    const int tot = n0 + n1c;
    float b0 = -3.0e38f, b1 = -3.0e38f;
    int j0 = 0, j1 = 0;
    for (int t = 0; t < tot; ++t) {
      const bool is1 = (t >= n0);
      const int j = is1 ? (t - n0) : t;
      const int c = is1 ? c1 : c0;
      const int i = is1 ? 1 : 0;
      const int idx = c - j;
      float a = (j == 0) ? 0.0f : L(96 + 16 * i + j - 1);
      float b = (idx == 0) ? 0.0f : L(96 + 16 * i + 8 + idx - 1);
      float g = gumbel_draw(keys.v[2], keys.v[3],
                            2u * t9 + (uint32_t)(9 * i + j));
      float v = (a + b) + g;
      if (is1) { if (v > b1) { b1 = v; j1 = j; } }
      else     { if (v > b0) { b0 = v; j0 = j; } }
    }
    c1v[0] = j0; c1v[1] = c0 - j0; c1v[2] = j1; c1v[3] = c1 - j1;
  }
  uint32_t pk2 = 0;
  {  // li2: 4 tasks, J=5 static with validity guard (low overhead per draw)
#pragma unroll
    for (int i = 0; i < 4; ++i) {
      int c = c1v[i];
      float best = -3.0e38f; int bj2 = 0;
#pragma unroll
      for (int j = 0; j < 5; ++j) {
        float g = gumbel_draw(keys.v[4], keys.v[5],
                              4u * t9 + (uint32_t)(i * 9 + j));
        int idx = c - j;
        int cl = min(max(idx, 1), 4);
        float b = L(64 + (2 * i + 1) * 4 + cl - 1);
        float bf = (idx == 0) ? 0.0f : b;
        float a = (j == 0) ? 0.0f : L(64 + (2 * i) * 4 + j - 1);
        float v = (a + bf) + g;
        if (idx >= 0 && idx <= 4 && v > best) { best = v; bj2 = j; }
      }
      pk2 |= ((uint32_t)bj2 << (8 * i)) | ((uint32_t)(c - bj2) << (8 * i + 4));
    }
  }
  uint64_t pk64 = 0;
  {  // li3: 8 tasks, J=3 static with validity guard
    const uint32_t sk0 = keys.v[6], sk1 = keys.v[7];
    const uint32_t fb0 = 8u * t9;
#pragma unroll 2
    for (int i = 0; i < 8; ++i) {
      int c = (int)((pk2 >> (4 * i)) & 15u);
      float aL1 = L(32 + 2 * i), aL2 = L(48 + 2 * i);
      float bR1 = L(32 + 2 * i + 1), bR2 = L(48 + 2 * i + 1);
      uint32_t fb = fb0 + (uint32_t)(i * 9);
      float best = -3.0e38f; int bj3 = 0;
#pragma unroll
      for (int j = 0; j < 3; ++j) {
        float g = gumbel_draw(sk0, sk1, fb + (uint32_t)j);
        int idx = c - j;
        float bf = (idx == 1) ? bR1 : ((idx == 2) ? bR2 : 0.0f);
        float af = (j == 0) ? 0.0f : ((j == 1) ? aL1 : aL2);
        float v = (af + bf) + g;
        if (idx >= 0 && idx <= 2 && v > best) { best = v; bj3 = j; }
      }
      pk64 |= ((uint64_t)(uint32_t)bj3 << (8 * i)) |
              ((uint64_t)(uint32_t)(c - bj3) << (8 * i + 4));
    }
  }
  {  // li4: draws ONLY for c==1 leaf pairs (c=0 -> bj=0, c=2 -> bj=1)
    const uint32_t sk0 = keys.v[8], sk1 = keys.v[9];
    const uint32_t fb0 = 16u * t9;
    float* bs = out + p * (B * 32) + node * 256 + e;
    uint64_t lst = 0; int m4 = 0;
#pragma unroll
    for (int i = 0; i < 16; ++i) {
      int c = (int)((uint32_t)(pk64 >> (4 * i)) & 15u);
      if (c == 1) {
        lst |= ((uint64_t)(uint32_t)i) << (4 * m4);
        ++m4;
      } else {
        int bj = c >> 1;                        // 0->0, 2->1
        bs[16 * i] = (float)bj;
        bs[16 * i + 8] = (float)(c - bj);
      }
    }
    for (int tt = 0; tt < m4; ++tt) {
      int i = (int)((lst >> (4 * tt)) & 15u);
      float thL = L(2 * i);
      float thR = L(2 * i + 1);
      uint32_t fb = fb0 + (uint32_t)(i * 9);
      float g0 = gumbel_draw(sk0, sk1, fb);       // j=0: 0 + thR
      float g1 = gumbel_draw(sk0, sk1, fb + 1u);  // j=1: thL + 0
      int bj = ((thL + g1) > (thR + g0)) ? 1 : 0; // first-max: strict >
      bs[16 * i] = (float)bj;
      bs[16 * i + 8] = (float)(1 - bj);
    }
  }
#undef L
}

extern "C" void kernel_launch(void* const* d_in, const int* in_sizes, int n_in,
                              void* d_out, int out_size, void* d_ws, size_t ws_size,
                              hipStream_t stream) {
  const float* scores = (const float*)d_in[0];
  float* out = (float*)d_out;
  const int nnodes = in_sizes[0] / (32 * 8);   // 8192
  const int B = nnodes * 8;                    // 65536 rows

  // key = jax.random.key(42); per level: key, sub = split(key)
  // (partitionable threefry: new = tf(key,(0,0)), sub = tf(key,(0,1)))
  TFKeys K;
  uint32_t k0 = 0u, k1 = 42u;
  for (int t = 0; t < 5; ++t) {
    uint32_t n0, n1, s0, s1;
    tf2x32(k0, k1, 0u, 0u, n0, n1);
    tf2x32(k0, k1, 0u, 1u, s0, s1);
    K.v[2 * t] = s0; K.v[2 * t + 1] = s1;
    k0 = n0; k1 = n1;
  }

  dim3 grid((unsigned)(B / 32)), block(64);
  hipLaunchKernelGGL(simple_sampler_kernel, grid, block, 0, stream,
                     scores, out, nnodes, K);
}